// Round 3
// baseline (90.450 us; speedup 1.0000x reference)
//
#include <hip/hip_runtime.h>
#include <hip/hip_bf16.h>
#include <stdint.h>

// RoICrop: bilinear sampling with border clamp.
// input1: [R=128, C=512, H=37, W=37] f32
// input2: [R=128, 14, 14, 2] f32 in [-1,1], (y, x)
// out:    [R, C, 14, 14] f32
//
// Block = (roi, 32 channels) -> 8 chunks of 4 planes (21904 B each).
// Double-buffered LDS staging via global_load_lds width-16, raw s_barrier +
// COUNTED s_waitcnt vmcnt(N) so the next chunk's DMA flies across the barrier
// while the current chunk is computed (no vmcnt(0) drain in the loop).
// Per-wave global_load_lds counts per chunk: waves {0,1}=6, {2,3}=5.

#define RR 128
#define CC 512
#define HH 37
#define WW 37
#define GS 14
#define NP (GS * GS)              // 196
#define PLANE (HH * WW)           // 1369
#define CPB 4                     // channels (planes) per chunk
#define CHUNK_BYTES (CPB * PLANE * 4)   // 21904
#define NCHUNK 22                 // 21*1024 + 400 (last: 25 lanes)
#define KITER 8                   // chunks per block
#define CGROUP (CPB * KITER)      // 32 channels per block
#define NBLK (RR * (CC / CGROUP)) // 2048

typedef __attribute__((address_space(1))) const void gconst_void;
typedef __attribute__((address_space(3))) void lds_void;

__device__ __forceinline__ void memfence_barrier() {
    asm volatile("" ::: "memory");
    __builtin_amdgcn_s_barrier();
    __builtin_amdgcn_sched_barrier(0);
    asm volatile("" ::: "memory");
}

__device__ __forceinline__ void stage_chunk(const char* __restrict__ src,
                                            char* dst, int wave, int lane) {
    // wave-uniform trip counts: waves 0,1 -> 6 instrs; waves 2,3 -> 5.
    for (int ch = wave; ch < NCHUNK; ch += 4) {
        const int off = ch * 1024 + lane * 16;
        if (off + 16 <= CHUNK_BYTES) {
            __builtin_amdgcn_global_load_lds(
                (gconst_void*)(src + off), (lds_void*)(dst + off), 16, 0, 0);
        }
    }
}

__global__ __launch_bounds__(256) void roicrop_kernel(
    const float* __restrict__ feat,
    const float* __restrict__ grid,
    float* __restrict__ out)
{
    __shared__ float  s_buf[2][CPB * PLANE];   // 2 x 21904 B
    __shared__ float4 s_pt[NP];                // 3136 B

    const int blk = blockIdx.x;
    const int r   = blk / (CC / CGROUP);       // CC/CGROUP = 16
    const int g   = blk % (CC / CGROUP);
    const int c0  = g * CGROUP;
    const int tid  = threadIdx.x;
    const int wave = tid >> 6;
    const int lane = tid & 63;

    const char* src0 = (const char*)(feat + ((size_t)r * CC + c0) * PLANE);

    // ---- prologue: fire chunk0 + chunk1 DMA, grid math overlaps ----
    stage_chunk(src0,               (char*)s_buf[0], wave, lane);
    stage_chunk(src0 + CHUNK_BYTES, (char*)s_buf[1], wave, lane);

    if (tid < NP) {
        float2 g2 = reinterpret_cast<const float2*>(grid)[(size_t)r * NP + tid];
        float y = (g2.x + 1.0f) * 18.0f;   // (H-1)/2
        float x = (g2.y + 1.0f) * 18.0f;
        float y0f = floorf(y), x0f = floorf(x);
        int y0 = (int)y0f, x0 = (int)x0f;
        int y0i = min(max(y0,     0), HH - 1);
        int y1i = min(max(y0 + 1, 0), HH - 1);
        int x0i = min(max(x0,     0), WW - 1);
        int x1i = min(max(x0 + 1, 0), WW - 1);
        uint32_t oa = (uint32_t)(y0i * WW + x0i) | ((uint32_t)(y0i * WW + x1i) << 16);
        uint32_t ob = (uint32_t)(y1i * WW + x0i) | ((uint32_t)(y1i * WW + x1i) << 16);
        s_pt[tid] = make_float4(y - y0f, x - x0f,
                                __uint_as_float(oa), __uint_as_float(ob));
    }

    asm volatile("s_waitcnt lgkmcnt(0)" ::: "memory");      // s_pt drained
    if (wave < 2) asm volatile("s_waitcnt vmcnt(6)" ::: "memory");  // chunk0 landed
    else          asm volatile("s_waitcnt vmcnt(5)" ::: "memory");
    memfence_barrier();

    // ---- hoist this thread's 4 sample points into registers ----
    int cl = 0;
    float wy[4], wx[4];
    int o00[4], o01[4], o10[4], o11[4];
    if (tid < NP) {
        cl = tid / 49;
        const int j = tid - cl * 49;
        #pragma unroll
        for (int t = 0; t < 4; ++t) {
            float4 pt = s_pt[j * 4 + t];
            wy[t] = pt.x; wx[t] = pt.y;
            uint32_t oa = __float_as_uint(pt.z);
            uint32_t ob = __float_as_uint(pt.w);
            o00[t] = oa & 0xffffu; o01[t] = oa >> 16;
            o10[t] = ob & 0xffffu; o11[t] = ob >> 16;
        }
    }

    // ---- main loop: compute chunk k, prefetch chunk k+2 ----
    for (int k = 0; k < KITER; ++k) {
        if (tid < NP) {
            const float* pl = &s_buf[k & 1][cl * PLANE];
            float4 o;
            #pragma unroll
            for (int t = 0; t < 4; ++t) {
                float v00 = pl[o00[t]];
                float v01 = pl[o01[t]];
                float v10 = pl[o10[t]];
                float v11 = pl[o11[t]];
                float top = v00 + (v01 - v00) * wx[t];
                float bot = v10 + (v11 - v10) * wx[t];
                (&o.x)[t] = top + (bot - top) * wy[t];
            }
            float4* dst = reinterpret_cast<float4*>(
                out + ((size_t)r * CC + c0 + 4 * k) * NP);
            dst[tid] = o;
        }
        memfence_barrier();   // barrier B: all waves done reading s_buf[k&1]

        if (k < KITER - 2)
            stage_chunk(src0 + (size_t)(k + 2) * CHUNK_BYTES,
                        (char*)s_buf[k & 1], wave, lane);

        if (k < KITER - 1) {
            if (k < KITER - 2) {
                // newest events per wave: store_k (>=1) + chunk_{k+2} (6|5);
                // waiting past them drains chunk_{k+1}.
                if (wave < 2) asm volatile("s_waitcnt vmcnt(7)" ::: "memory");
                else          asm volatile("s_waitcnt vmcnt(6)" ::: "memory");
            } else {
                // k == KITER-2: only store_k newer than chunk_{k+1}
                asm volatile("s_waitcnt vmcnt(1)" ::: "memory");
            }
            memfence_barrier();   // barrier A: chunk k+1 visible to all
        }
    }
}

extern "C" void kernel_launch(void* const* d_in, const int* in_sizes, int n_in,
                              void* d_out, int out_size, void* d_ws, size_t ws_size,
                              hipStream_t stream) {
    const float* feat = (const float*)d_in[0];
    const float* grid = (const float*)d_in[1];
    float* out = (float*)d_out;
    roicrop_kernel<<<dim3(NBLK), dim3(256), 0, stream>>>(feat, grid, out);
}

// Round 4
// 74.468 us; speedup vs baseline: 1.2146x; 1.2146x over previous
//
#include <hip/hip_runtime.h>
#include <hip/hip_bf16.h>
#include <stdint.h>

// RoICrop: bilinear sampling with border clamp.
// input1: [R=128, C=512, H=37, W=37] f32
// input2: [R=128, 14, 14, 2] f32 in [-1,1], (y, x)
// out:    [R, C, 14, 14] f32
//
// BARRIER-FREE design: block = (roi, 4 channels); wave w owns channel c0+w
// end-to-end. Each wave stages its own 5476-B plane into its own LDS region
// (global_load_lds w16), computes all 196 grid points into REGISTERS while
// the DMA flies, waits on its OWN vmcnt(0) (per-wave counter), gathers, and
// stores non-temporally. No s_barrier anywhere; no cross-wave coupling;
// all 64 lanes active.

#define RR 128
#define CC 512
#define HH 37
#define WW 37
#define NP 196                   // 14*14
#define PLANE 1369               // 37*37 floats = 5476 B
#define PLANE_PAD 1376           // pad to 5504 B (128B-aligned stride)
#define NBLK (RR * (CC / 4))     // 16384

typedef __attribute__((address_space(1))) const void gconst_void;
typedef __attribute__((address_space(3))) void lds_void;

__global__ __launch_bounds__(256) void roicrop_kernel(
    const float* __restrict__ feat,
    const float* __restrict__ grid,
    float* __restrict__ out)
{
    __shared__ float s_plane[4][PLANE_PAD];   // 22016 B

    const int blk = blockIdx.x;
    const int r   = blk >> 7;                 // / (CC/4)=128
    const int cb  = blk & 127;
    const int c   = cb * 4 + (threadIdx.x >> 6);   // this wave's channel
    const int wave = threadIdx.x >> 6;
    const int lane = threadIdx.x & 63;

    // ---- 1) fire this wave's plane DMA (7 instrs: 5 full + tail16 + tail4) ----
    const char* srcb = (const char*)(feat + ((size_t)r * CC + c) * PLANE);
    char* dstb = (char*)&s_plane[wave][0];
    #pragma unroll
    for (int ch = 0; ch < 5; ++ch) {
        __builtin_amdgcn_global_load_lds(
            (gconst_void*)(srcb + ch * 1024 + lane * 16),
            (lds_void*)(dstb + ch * 1024 + lane * 16), 16, 0, 0);
    }
    if (lane < 22) {   // bytes 5120..5471
        __builtin_amdgcn_global_load_lds(
            (gconst_void*)(srcb + 5120 + lane * 16),
            (lds_void*)(dstb + 5120 + lane * 16), 16, 0, 0);
    }
    if (lane == 0) {   // final float, bytes 5472..5475
        __builtin_amdgcn_global_load_lds(
            (gconst_void*)(srcb + 5472 + lane * 4),
            (lds_void*)(dstb + 5472 + lane * 4), 4, 0, 0);
    }

    // ---- 2) grid math -> registers (overlaps DMA; redundant per wave, free) ----
    const float2* gp = reinterpret_cast<const float2*>(grid) + (size_t)r * NP;
    float wy[4], wx[4];
    uint32_t pa[4], pb[4];
    #pragma unroll
    for (int t = 0; t < 4; ++t) {
        const int p = lane + 64 * t;
        wy[t] = 0.f; wx[t] = 0.f; pa[t] = 0; pb[t] = 0;
        if (p < NP) {
            float2 g2 = gp[p];
            float y = (g2.x + 1.0f) * 18.0f;   // (H-1)/2
            float x = (g2.y + 1.0f) * 18.0f;
            float y0f = floorf(y), x0f = floorf(x);
            wy[t] = y - y0f; wx[t] = x - x0f;
            int y0 = (int)y0f, x0 = (int)x0f;
            int y0i = min(max(y0,     0), HH - 1);
            int y1i = min(max(y0 + 1, 0), HH - 1);
            int x0i = min(max(x0,     0), WW - 1);
            int x1i = min(max(x0 + 1, 0), WW - 1);
            pa[t] = (uint32_t)(y0i * WW + x0i) | ((uint32_t)(y0i * WW + x1i) << 16);
            pb[t] = (uint32_t)(y1i * WW + x0i) | ((uint32_t)(y1i * WW + x1i) << 16);
        }
    }

    // ---- 3) wait for OWN plane only (per-wave vmcnt; no barrier) ----
    asm volatile("s_waitcnt vmcnt(0)" ::: "memory");
    __builtin_amdgcn_sched_barrier(0);

    // ---- 4) gather + lerp + non-temporal store ----
    const float* pl = &s_plane[wave][0];
    float* dstp = out + ((size_t)r * CC + c) * NP;
    #pragma unroll
    for (int t = 0; t < 4; ++t) {
        const int p = lane + 64 * t;
        if (p < NP) {
            float v00 = pl[pa[t] & 0xffffu];
            float v01 = pl[pa[t] >> 16];
            float v10 = pl[pb[t] & 0xffffu];
            float v11 = pl[pb[t] >> 16];
            float top = v00 + (v01 - v00) * wx[t];
            float bot = v10 + (v11 - v10) * wx[t];
            __builtin_nontemporal_store(top + (bot - top) * wy[t], dstp + p);
        }
    }
}

extern "C" void kernel_launch(void* const* d_in, const int* in_sizes, int n_in,
                              void* d_out, int out_size, void* d_ws, size_t ws_size,
                              hipStream_t stream) {
    const float* feat = (const float*)d_in[0];
    const float* grid = (const float*)d_in[1];
    float* out = (float*)d_out;
    roicrop_kernel<<<dim3(NBLK), dim3(256), 0, stream>>>(feat, grid, out);
}